// Round 11
// baseline (237.882 us; speedup 1.0000x reference)
//
#include <hip/hip_runtime.h>
#include <cmath>

// LocalHolder2D: out = w3*log10(maxpool3(x)) + w5*log10(maxpool5(x)) + w7*log10(maxpool7(x))
// x: (8,64,256,256) fp32, strictly positive => -inf padding == 0 padding.
// One wave = 256-wide rows (64 lanes x float4), rolling down a 32-row strip.
//
// R1-R16: EVERY hand-pipelined lever neutral at ~81us kernel: MLP depth
//   (R9), NT/cached stores (R10), occupancy (R12), LDS staging (R13),
//   continuous streaming (R14), address-phase swizzle (R15), read-volume
//   cut 229->159MB (R16: read lane at 1.95 TB/s, well below its own 2.9
//   ceiling => read lane NOT binding; time pinned anyway).
// R17 (this): remove the ONE ingredient all eight variants shared and no
//   LN-class kernel has: the asm-volatile load + hand-counted s_waitcnt
//   scaffolding. Each asm("...":::"memory") is a full compiler barrier --
//   it defeats the scheduler's software pipelining and load/store/VALU
//   interleave that lets LN hit 5.2 TB/s combined (m219) and RMSNorm 4.9
//   (m146) vs our 3.6 max. Guide G7/m141: compiler waitcnt scheduling is
//   near-optimal; order-pinning costs. This is the anti-R8: plain vf4
//   loads/stores, full unroll, __restrict__, compiler owns everything.
//   Same 32-row strip + 7-reg rolling window as R16 (read amp 1.19).

#define IMG_H 256
#define IMG_W 256
#define RPW   32    // output rows per wave (strip)

typedef float vf4 __attribute__((ext_vector_type(4)));

// lane i <- lane i-1, zero at lane 0  (DPP wf_shr1; invalid lane -> old=0)
__device__ __forceinline__ float dpp_left(float v) {
  return __int_as_float(
      __builtin_amdgcn_update_dpp(0, __float_as_int(v), 0x138, 0xF, 0xF, true));
}
// lane i <- lane i+1, zero at lane 63 (DPP wf_shl1)
__device__ __forceinline__ float dpp_right(float v) {
  return __int_as_float(
      __builtin_amdgcn_update_dpp(0, __float_as_int(v), 0x130, 0xF, 0xF, true));
}

__device__ __forceinline__ vf4 vmax4(vf4 a, vf4 b) {
  vf4 r;
  r.x = fmaxf(a.x, b.x); r.y = fmaxf(a.y, b.y);
  r.z = fmaxf(a.z, b.z); r.w = fmaxf(a.w, b.w);
  return r;
}

struct PS { float p1, p2, p3, s1, s2, s3, f; };

__device__ __forceinline__ PS make_ps(vf4 a) {
  PS r;
  r.p1 = a.x;
  r.p2 = fmaxf(a.x, a.y);
  r.p3 = fmaxf(r.p2, a.z);
  r.s1 = a.w;
  r.s2 = fmaxf(a.z, a.w);
  r.s3 = fmaxf(a.y, r.s2);
  r.f  = fmaxf(r.p2, r.s2);
  return r;
}

// One output row from its 7-row input window (vertical max -> in-lane
// prefix/suffix + DPP neighbor exchange for horizontal max -> 3x log2).
__device__ __forceinline__ vf4 row_out(vf4 wm3, vf4 wm2, vf4 wm1, vf4 wc,
                                       vf4 wp1, vf4 wp2, vf4 wp3,
                                       float w3, float w5, float w7) {
  vf4 v1 = vmax4(vmax4(wm1, wc), wp1);
  vf4 v2 = vmax4(v1, vmax4(wm2, wp2));
  vf4 v3 = vmax4(v2, vmax4(wm3, wp3));

  PS a1 = make_ps(v1), a2 = make_ps(v2), a3 = make_ps(v3);

  float L1s1 = dpp_left(a1.s1);
  float L2s1 = dpp_left(a2.s1);
  float L2s2 = dpp_left(a2.s2);
  float L3s1 = dpp_left(a3.s1);
  float L3s2 = dpp_left(a3.s2);
  float L3s3 = dpp_left(a3.s3);

  float R1p1 = dpp_right(a1.p1);
  float R2p1 = dpp_right(a2.p1);
  float R2p2 = dpp_right(a2.p2);
  float R3p1 = dpp_right(a3.p1);
  float R3p2 = dpp_right(a3.p2);
  float R3p3 = dpp_right(a3.p3);

  float m3_0 = fmaxf(L1s1, a1.p2);
  float m3_1 = a1.p3;
  float m3_2 = a1.s3;
  float m3_3 = fmaxf(a1.s2, R1p1);

  float m5_0 = fmaxf(L2s2, a2.p3);
  float m5_1 = fmaxf(L2s1, a2.f);
  float m5_2 = fmaxf(a2.f, R2p1);
  float m5_3 = fmaxf(a2.s3, R2p2);

  float m7_0 = fmaxf(L3s3, a3.f);
  float m7_1 = fmaxf(fmaxf(L3s2, a3.f), R3p1);
  float m7_2 = fmaxf(fmaxf(L3s1, a3.f), R3p2);
  float m7_3 = fmaxf(a3.f, R3p3);

  vf4 o;
  o.x = fmaf(w7, __log2f(m7_0), fmaf(w5, __log2f(m5_0), w3 * __log2f(m3_0)));
  o.y = fmaf(w7, __log2f(m7_1), fmaf(w5, __log2f(m5_1), w3 * __log2f(m3_1)));
  o.z = fmaf(w7, __log2f(m7_2), fmaf(w5, __log2f(m5_2), w3 * __log2f(m3_2)));
  o.w = fmaf(w7, __log2f(m7_3), fmaf(w5, __log2f(m5_3), w3 * __log2f(m3_3)));
  return o;
}

__global__ __launch_bounds__(64, 4) void holder_kernel(
    const float* __restrict__ x, float* __restrict__ out,
    float w3, float w5, float w7)
{
  const int lane  = threadIdx.x;      // 64-thread block = one wave
  const int img   = blockIdx.x;       // 0..511 (consecutive -> XCD spread)
  const int strip = blockIdx.y;       // 0..7
  const int r0    = strip * RPW;

  const float* px = x + (size_t)img * (IMG_H * IMG_W) + lane * 4;
  float*       po = out + (size_t)img * (IMG_H * IMG_W) + lane * 4;

  const vf4 vzero = (vf4)0.0f;

  // Rolling 7-row window: before iteration k, win0..win5 = rows r-3..r+2
  // (r = r0+k); win6 (row r+3) is loaded inside the iteration. All loads
  // use clamped addresses (always valid) + select-zero for pad rows.
  vf4 win0, win1, win2, win3, win4, win5, win6;
  {
    int rr, rc; vf4 t;
    rr = r0 - 3; rc = rr < 0 ? 0 : rr;
    t = *(const vf4*)(px + rc * IMG_W); win0 = rr < 0 ? vzero : t;
    rr = r0 - 2; rc = rr < 0 ? 0 : rr;
    t = *(const vf4*)(px + rc * IMG_W); win1 = rr < 0 ? vzero : t;
    rr = r0 - 1; rc = rr < 0 ? 0 : rr;
    t = *(const vf4*)(px + rc * IMG_W); win2 = rr < 0 ? vzero : t;
    win3 = *(const vf4*)(px + (r0 + 0) * IMG_W);
    win4 = *(const vf4*)(px + (r0 + 1) * IMG_W);
    win5 = *(const vf4*)(px + (r0 + 2) * IMG_W);
  }

#pragma unroll
  for (int k = 0; k < RPW; ++k) {
    const int r  = r0 + k;
    const int rn = r + 3;
    const int rc = rn > IMG_H - 1 ? IMG_H - 1 : rn;
    vf4 t = *(const vf4*)(px + rc * IMG_W);
    win6 = rn > IMG_H - 1 ? vzero : t;

    vf4 o = row_out(win0, win1, win2, win3, win4, win5, win6, w3, w5, w7);
    *(vf4*)(po + r * IMG_W) = o;

    win0 = win1; win1 = win2; win2 = win3;
    win3 = win4; win4 = win5; win5 = win6;
  }
}

extern "C" void kernel_launch(void* const* d_in, const int* in_sizes, int n_in,
                              void* d_out, int out_size, void* d_ws, size_t ws_size,
                              hipStream_t stream) {
  const float* x = (const float*)d_in[0];
  float* out = (float*)d_out;

  const int n_img = in_sizes[0] / (IMG_H * IMG_W);  // B*C = 512

  // closed-form OLS slope weights (H*W cancels in centering), log10(2) folded in
  const double l0 = log10(3.0), l1 = log10(5.0), l2 = log10(7.0);
  const double m  = (l0 + l1 + l2) / 3.0;
  const double c0 = l0 - m, c1 = l1 - m, c2 = l2 - m;
  const double s  = c0 * c0 + c1 * c1 + c2 * c2;
  const double LG2 = 0.30102999566398119521;  // log10(2)
  const float w3 = (float)(c0 / s * LG2);
  const float w5 = (float)(c1 / s * LG2);
  const float w7 = (float)(c2 / s * LG2);

  hipLaunchKernelGGL(holder_kernel, dim3(n_img, IMG_H / RPW), dim3(64),
                     0, stream, x, out, w3, w5, w7);
}